// Round 1
// baseline (186.942 us; speedup 1.0000x reference)
//
#include <hip/hip_runtime.h>
#include <hip/hip_bf16.h>
#include <stdint.h>

// Problem constants
#define B_ 32
#define N_ 4096
#define M_ 256
#define L_ 128
#define H_ 4
#define BN_ (B_ * N_)          // 131072 flattened rows

typedef __bf16 bf16x8 __attribute__((ext_vector_type(8)));
typedef float  f32x4  __attribute__((ext_vector_type(4)));

__device__ __forceinline__ unsigned short f2bf(float f) {
    // round-to-nearest-even f32 -> bf16 (inputs are normal floats)
    unsigned int u = __float_as_uint(f);
    u += 0x7fffu + ((u >> 16) & 1u);
    return (unsigned short)(u >> 16);
}
__device__ __forceinline__ unsigned int pack2(float lo, float hi) {
    return (unsigned int)f2bf(lo) | ((unsigned int)f2bf(hi) << 16);
}

// ---------------------------------------------------------------------------
// Kernel 1: transpose+cast V,U (H,M,L) f32 -> Vt,Ut (H,L,M) bf16.
// Makes MFMA B-fragments K(=m)-contiguous. 131072 elems each, trivial.
// ---------------------------------------------------------------------------
__global__ void prep_vu(const float* __restrict__ V, const float* __restrict__ U,
                        unsigned short* __restrict__ Vt, unsigned short* __restrict__ Ut) {
    int idx = blockIdx.x * 256 + threadIdx.x;   // over H*L*M = 131072, m fastest
    int m = idx & (M_ - 1);
    int l = (idx >> 8) & (L_ - 1);
    int h = idx >> 15;
    Vt[idx] = f2bf(V[((size_t)h * M_ + m) * L_ + l]);
    Ut[idx] = f2bf(U[((size_t)h * M_ + m) * L_ + l]);
}

// ---------------------------------------------------------------------------
// Kernel 2: fused GEMM -> logits.
// logits[b,h,n] = sum_l tanh(sum_m x*V) * sigmoid(sum_m x*U) * w[h,l]
// Per block: one h, 128 rows of x, all 128 l-cols, both V and U.
// 4 waves, each wave: 32 rows (2 rowfrags) x 128 cols x {V,U} acc = 128 VGPRs.
// BK=64, K=256 -> 4 K-steps. XOR-swizzled LDS (byte ^= (row&7)<<4) to kill
// the stride-128B bank conflict on ds_read_b128 (G4).
// Grid: tile-major, h outer -> h=0 sweep streams x from HBM once (134MB),
// h=1..3 sweeps hit L3 (x fits in 256MB L3).
// ---------------------------------------------------------------------------
#define BM 128
#define BK 64

__global__ __launch_bounds__(256, 2)
void gemm_logits(const float* __restrict__ x,
                 const unsigned short* __restrict__ Vt,
                 const unsigned short* __restrict__ Ut,
                 const float* __restrict__ w,
                 float* __restrict__ logits) {
    __shared__ __align__(16) unsigned short xs[BM * BK];   // 16 KB
    __shared__ __align__(16) unsigned short vs[L_ * BK];   // 16 KB
    __shared__ __align__(16) unsigned short us[L_ * BK];   // 16 KB
    __shared__ float wl[L_];

    const int h    = blockIdx.x >> 10;         // 1024 tiles per h
    const int tile = blockIdx.x & 1023;
    const int row0 = tile * BM;
    const int tid  = threadIdx.x;
    const int lane = tid & 63;
    const int wave = tid >> 6;

    if (tid < L_) wl[tid] = w[h * L_ + tid];

    f32x4 accV[2][8], accU[2][8];
#pragma unroll
    for (int rf = 0; rf < 2; ++rf)
#pragma unroll
        for (int cf = 0; cf < 8; ++cf) {
            accV[rf][cf] = (f32x4){0.f, 0.f, 0.f, 0.f};
            accU[rf][cf] = (f32x4){0.f, 0.f, 0.f, 0.f};
        }

    const unsigned short* Vh = Vt + (size_t)h * L_ * M_;
    const unsigned short* Uh = Ut + (size_t)h * L_ * M_;

    const int g = lane >> 4;    // k-group 0..3
    const int c = lane & 15;    // row (A) / col (B) within fragment

    for (int ks = 0; ks < 4; ++ks) {
        const int k0 = ks * BK;
        __syncthreads();   // previous-iter LDS reads done (also fences wl)

        // ---- stage x tile (f32 -> bf16), 128x64, swizzled ----
#pragma unroll
        for (int p = 0; p < 4; ++p) {
            int row = p * 32 + (tid >> 3);
            int kk  = (tid & 7) * 8;
            const float* gx = x + (size_t)(row0 + row) * M_ + k0 + kk;
            float4 a = *(const float4*)gx;
            float4 b = *(const float4*)(gx + 4);
            uint4 o;
            o.x = pack2(a.x, a.y); o.y = pack2(a.z, a.w);
            o.z = pack2(b.x, b.y); o.w = pack2(b.z, b.w);
            int byte = (row * BK + kk) * 2;
            byte ^= (row & 7) << 4;
            *(uint4*)((char*)xs + byte) = o;
        }
        // ---- stage Vt/Ut chunks (bf16 passthrough), 128x64, swizzled ----
#pragma unroll
        for (int p = 0; p < 4; ++p) {
            int l  = p * 32 + (tid >> 3);
            int kk = (tid & 7) * 8;
            uint4 v = *(const uint4*)(Vh + (size_t)l * M_ + k0 + kk);
            uint4 u = *(const uint4*)(Uh + (size_t)l * M_ + k0 + kk);
            int byte = (l * BK + kk) * 2;
            byte ^= (l & 7) << 4;
            *(uint4*)((char*)vs + byte) = v;
            *(uint4*)((char*)us + byte) = u;
        }
        __syncthreads();

        // ---- MFMA: 2 ksubs x (2 A-frags, 8 colfrags x {V,U}) ----
#pragma unroll
        for (int ksub = 0; ksub < 2; ++ksub) {
            bf16x8 afr[2];
#pragma unroll
            for (int rf = 0; rf < 2; ++rf) {
                int row = wave * 32 + rf * 16 + c;
                int byte = (row * BK + ksub * 32 + g * 8) * 2;
                byte ^= (row & 7) << 4;
                afr[rf] = *(const bf16x8*)((const char*)xs + byte);
            }
#pragma unroll
            for (int cf = 0; cf < 8; ++cf) {
                int l = cf * 16 + c;
                int byte = (l * BK + ksub * 32 + g * 8) * 2;
                byte ^= (l & 7) << 4;
                bf16x8 bv = *(const bf16x8*)((const char*)vs + byte);
                bf16x8 bu = *(const bf16x8*)((const char*)us + byte);
#pragma unroll
                for (int rf = 0; rf < 2; ++rf) {
                    accV[rf][cf] = __builtin_amdgcn_mfma_f32_16x16x32_bf16(afr[rf], bv, accV[rf][cf], 0, 0, 0);
                    accU[rf][cf] = __builtin_amdgcn_mfma_f32_16x16x32_bf16(afr[rf], bu, accU[rf][cf], 0, 0, 0);
                }
            }
        }
    }

    // ---- epilogue: tanh*sigmoid*w, reduce over l, write logits ----
    // C/D layout (m89): col = lane&15, row = (lane>>4)*4 + reg.
#pragma unroll
    for (int rf = 0; rf < 2; ++rf) {
        float plog[4] = {0.f, 0.f, 0.f, 0.f};
#pragma unroll
        for (int cf = 0; cf < 8; ++cf) {
            float wv = wl[cf * 16 + c];
#pragma unroll
            for (int i = 0; i < 4; ++i) {
                float vv = accV[rf][cf][i];
                float uu = accU[rf][cf][i];
                vv = fminf(fmaxf(vv, -20.f), 20.f);       // avoid inf/inf
                float e2v = __expf(2.f * vv);
                float t = __fdividef(e2v - 1.f, e2v + 1.f);         // tanh
                float s = __fdividef(1.f, 1.f + __expf(-uu));       // sigmoid
                plog[i] += t * s * wv;
            }
        }
#pragma unroll
        for (int i = 0; i < 4; ++i) {
            float v = plog[i];
            v += __shfl_xor(v, 1);
            v += __shfl_xor(v, 2);
            v += __shfl_xor(v, 4);
            v += __shfl_xor(v, 8);      // sum over the 16 col-lanes
            if (c == 0) {
                int rowflat = row0 + wave * 32 + rf * 16 + g * 4 + i;
                int b = rowflat >> 12;           // / N_
                int n = rowflat & (N_ - 1);
                logits[((size_t)b * H_ + h) * N_ + n] = v;
            }
        }
    }
}

// ---------------------------------------------------------------------------
// Kernel 3: masked softmax^2. a_n = e_n^2 / sum(e^2), e = m*exp(m*logit).
// (First normalization cancels algebraically.) Writes att in (H,B,N) order.
// ---------------------------------------------------------------------------
__global__ __launch_bounds__(256)
void softmax_att(const float* __restrict__ logits, const float* __restrict__ masks,
                 float* __restrict__ att) {
    const int bh = blockIdx.x;       // b*H + h
    const int b = bh >> 2, h = bh & 3;
    __shared__ float e2s[N_];        // 16 KB
    __shared__ float red[4];
    const int tid = threadIdx.x;

    float sum = 0.f;
#pragma unroll
    for (int i = 0; i < N_ / 256; ++i) {
        int n = i * 256 + tid;
        float lg = logits[((size_t)b * H_ + h) * N_ + n];
        float mv = masks[(size_t)b * N_ + n];
        float e = mv * __expf(mv * lg);
        float e2 = e * e;
        e2s[n] = e2;
        sum += e2;
    }
#pragma unroll
    for (int off = 32; off >= 1; off >>= 1) sum += __shfl_xor(sum, off);
    if ((tid & 63) == 0) red[tid >> 6] = sum;
    __syncthreads();
    float S = red[0] + red[1] + red[2] + red[3];
    float inv = 1.f / S;
#pragma unroll
    for (int i = 0; i < N_ / 256; ++i) {
        int n = i * 256 + tid;
        att[((size_t)h * B_ + b) * N_ + n] = e2s[n] * inv;
    }
}

// ---------------------------------------------------------------------------
// Kernel 4/5: emb[b,h,m] = sum_n a[h,b,n] * x[b,n,m].
// Deterministic 2-stage: per-(b,chunk) partials in d_ws, then reduce.
// ---------------------------------------------------------------------------
#define NCH 32
#define CHUNK (N_ / NCH)   // 128

__global__ __launch_bounds__(256)
void emb_partial(const float* __restrict__ x, const float* __restrict__ att,
                 float* __restrict__ part) {
    const int bc = blockIdx.x;          // b*NCH + ch
    const int b = bc >> 5, ch = bc & 31;
    __shared__ float as[H_][CHUNK];
    const int tid = threadIdx.x;

    for (int i = tid; i < H_ * CHUNK; i += 256) {
        int hh = i >> 7;
        int j  = i & (CHUNK - 1);
        as[hh][j] = att[((size_t)hh * B_ + b) * N_ + ch * CHUNK + j];
    }
    __syncthreads();

    float a0 = 0.f, a1 = 0.f, a2 = 0.f, a3 = 0.f;
    const float* xp = x + ((size_t)b * N_ + ch * CHUNK) * M_ + tid;
#pragma unroll 4
    for (int j = 0; j < CHUNK; ++j) {
        float xv = xp[(size_t)j * M_];
        a0 += as[0][j] * xv;
        a1 += as[1][j] * xv;
        a2 += as[2][j] * xv;
        a3 += as[3][j] * xv;
    }
    float* pp = part + (size_t)bc * H_ * M_ + tid;
    pp[0 * M_] = a0; pp[1 * M_] = a1; pp[2 * M_] = a2; pp[3 * M_] = a3;
}

__global__ __launch_bounds__(256)
void emb_reduce(const float* __restrict__ part, float* __restrict__ emb) {
    int idx = blockIdx.x * 256 + threadIdx.x;   // over B*H*M = 32768
    int b = idx >> 10;                          // / (H*M)
    int r = idx & 1023;
    float s = 0.f;
#pragma unroll
    for (int ci = 0; ci < NCH; ++ci)
        s += part[((size_t)(b * NCH + ci)) * (H_ * M_) + r];
    emb[idx] = s;
}

// ---------------------------------------------------------------------------
extern "C" void kernel_launch(void* const* d_in, const int* in_sizes, int n_in,
                              void* d_out, int out_size, void* d_ws, size_t ws_size,
                              hipStream_t stream) {
    const float* x     = (const float*)d_in[0];
    const float* masks = (const float*)d_in[1];
    const float* V     = (const float*)d_in[2];
    const float* U     = (const float*)d_in[3];
    const float* w     = (const float*)d_in[4];

    float* att = (float*)d_out;                       // (H,B,N,1): 524288 f32
    float* emb = att + (size_t)H_ * B_ * N_;          // (B,H*M):   32768 f32

    // workspace layout
    char* ws = (char*)d_ws;
    unsigned short* Vt = (unsigned short*)ws;                         // 256 KB
    unsigned short* Ut = (unsigned short*)(ws + 262144);              // 256 KB
    float* logits      = (float*)(ws + 524288);                       // 2 MB (B,H,N)
    float* part        = (float*)(ws + 524288 + 2097152);             // 4 MB

    prep_vu   <<<(H_ * L_ * M_) / 256, 256, 0, stream>>>(V, U, Vt, Ut);
    gemm_logits<<<(BN_ / BM) * H_,      256, 0, stream>>>(x, Vt, Ut, w, logits);
    softmax_att<<<B_ * H_,              256, 0, stream>>>(logits, masks, att);
    emb_partial<<<B_ * NCH,             256, 0, stream>>>(x, att, part);
    emb_reduce <<<(B_ * H_ * M_) / 256, 256, 0, stream>>>(part, emb);
}